// Round 13
// baseline (86584.973 us; speedup 1.0000x reference)
//
#include <hip/hip_runtime.h>

#define NB 32
#define TENC 300
#define TDEC 500
#define NMEL 80
#define ENCD 512
#define PRE 256
#define ADIM 128
#define RD 8          // ring depth

// ---------------- workspace layout (float offsets) ----------------
#define OFF_DECINS 0ull                         // 500*32*256 = 4,096,000
#define OFF_H1M    4096000ull                   // prenet scratch (pre-loop only)
// rings alias the H1M region (H1M dead once k_loop starts)
#define OFF_AHR    4096000ull                   // 8*32768 = 262,144
#define OFF_DHR    (OFF_AHR + 262144ull)        // 262,144
#define OFF_CXR    (OFF_DHR + 262144ull)        // 8*16384 = 131,072
#define RINGS_N    655360ull
#define OFF_PM     8192000ull                   // 32*300*128 = 1,228,800
#define OFF_STATE  (OFF_PM + 1228800ull)        // = 9,420,800
#define OFF_AC     (OFF_STATE + 0ull)           // 32,768
#define OFF_DC     (OFF_STATE + 32768ull)       // 32,768
#define OFF_AW     (OFF_STATE + 65536ull)       // 9,600
#define OFF_AWC    (OFF_STATE + 75136ull)       // 9,600
#define OFF_E      (OFF_STATE + 84736ull)       // 9,600
#define OFF_SLOTS  (OFF_STATE + 94336ull)       // 256 slots + 16 l2 + gen (64B-aligned)
#define STATE_N    98440ull
#define OFF_QWT    (OFF_STATE + STATE_N)        // 131,072
#define OFF_PROJWT (OFF_QWT + 131072ull)        // 122,880
#define OFF_MWT    (OFF_PROJWT + 122880ull)     // 65,536
#define OFF_W1T    (OFF_MWT + 65536ull)         // 20,480
#define OFF_W2T    (OFF_W1T + 20480ull)         // 65,536

// ---------------- device-coherent (agent-scope, fence-free) helpers ----------------
__device__ __forceinline__ float gload(const float* p){
  return __hip_atomic_load(p, __ATOMIC_RELAXED, __HIP_MEMORY_SCOPE_AGENT);
}
__device__ __forceinline__ void gstore(float* p, float v){
  __hip_atomic_store(p, v, __ATOMIC_RELAXED, __HIP_MEMORY_SCOPE_AGENT);
}

// ---------------- tree grid barrier (low coherence-point polling load) ----------------
// arrive: 1 slot store/block.  16 aggregators each poll ONE 64B line (their 16 slots).
// block 0 polls the 16 l2 flags (one line).  everyone polls the single gen line.
__device__ __forceinline__ void gbar(unsigned* slots, unsigned epoch){
  __syncthreads();   // drains all waves' vmem before the slot store
  int tid = threadIdx.x, wg = blockIdx.x;
  unsigned* l2  = slots + 256;   // 16 u32, one line
  unsigned* gen = slots + 320;   // 1 u32, own line
  if (tid == 0)
    __hip_atomic_store(&slots[wg], epoch, __ATOMIC_RELAXED, __HIP_MEMORY_SCOPE_AGENT);
  if (wg < 16 && tid < 16){
    while (__hip_atomic_load(&slots[wg*16 + tid], __ATOMIC_RELAXED, __HIP_MEMORY_SCOPE_AGENT) < epoch) {}
  }
  if (wg < 16 && tid == 0)
    __hip_atomic_store(&l2[wg], epoch, __ATOMIC_RELAXED, __HIP_MEMORY_SCOPE_AGENT);
  if (wg == 0 && tid < 16){
    while (__hip_atomic_load(&l2[tid], __ATOMIC_RELAXED, __HIP_MEMORY_SCOPE_AGENT) < epoch) {}
  }
  if (wg == 0 && tid == 0)
    __hip_atomic_store(gen, epoch, __ATOMIC_RELAXED, __HIP_MEMORY_SCOPE_AGENT);
  if (tid == 0){
    while (__hip_atomic_load(gen, __ATOMIC_RELAXED, __HIP_MEMORY_SCOPE_AGENT) < epoch)
      __builtin_amdgcn_s_sleep(1);
  }
  __syncthreads();
}

// ---------------- threefry2x32 (matches JAX bit-exactly) ----------------
__host__ __device__ __forceinline__ unsigned rotl32(unsigned v, int r){ return (v<<r)|(v>>(32-r)); }

__host__ __device__ __forceinline__ void tf2x32(unsigned k0, unsigned k1, unsigned c0, unsigned c1,
                                                unsigned& y0, unsigned& y1){
  unsigned ks2 = k0 ^ k1 ^ 0x1BD11BDAu;
  unsigned x0 = c0 + k0, x1 = c1 + k1;
#define TFR(r) x0 += x1; x1 = rotl32(x1, r); x1 ^= x0;
  TFR(13) TFR(15) TFR(26) TFR(6)
  x0 += k1;  x1 += ks2 + 1u;
  TFR(17) TFR(29) TFR(16) TFR(24)
  x0 += ks2; x1 += k0 + 2u;
  TFR(13) TFR(15) TFR(26) TFR(6)
  x0 += k0;  x1 += k1 + 3u;
  TFR(17) TFR(29) TFR(16) TFR(24)
  x0 += k1;  x1 += ks2 + 4u;
  TFR(13) TFR(15) TFR(26) TFR(6)
  x0 += ks2; x1 += k0 + 5u;
#undef TFR
  y0 = x0; y1 = x1;
}

__device__ __forceinline__ float mask_scale(unsigned k0, unsigned k1, unsigned idx){
  unsigned y0, y1;
  tf2x32(k0, k1, 0u, idx, y0, y1);
  unsigned bits = y0 ^ y1;
  float u = __uint_as_float((bits >> 9) | 0x3f800000u) - 1.0f;
  return (u < 0.9f) ? (1.0f/0.9f) : 0.0f;
}

// ---------------- setup: zero small state + slots, weight transposes ----------------
__global__ __launch_bounds__(256) void k_setup(float* __restrict__ ws,
    const float* __restrict__ qW, const float* __restrict__ projW, const float* __restrict__ mW,
    const float* __restrict__ w1, const float* __restrict__ w2){
  long i = (long)blockIdx.x*256 + threadIdx.x;
  long stride = (long)gridDim.x*256;
  float* st = ws + OFF_STATE;
  for (long x = i; x < (long)STATE_N; x += stride) st[x] = 0.f;
  float* qWT = ws + OFF_QWT;     // [1024][128]
  for (long x = i; x < 1024*128; x += stride){ int u = x>>7, d = x&127; qWT[x] = qW[(size_t)d*1024+u]; }
  float* pWT = ws + OFF_PROJWT;  // [1536][80]
  for (long x = i; x < 1536*80; x += stride){ int k = x/80, m = x%80; pWT[x] = projW[(size_t)m*1536+k]; }
  float* mWT = ws + OFF_MWT;     // [512][128]
  for (long x = i; x < 512*128; x += stride){ int k = x>>7, d = x&127; mWT[x] = mW[(size_t)d*512+k]; }
  float* w1T = ws + OFF_W1T;     // [80][256]
  for (long x = i; x < 80*256; x += stride){ int m = x>>8, u = x&255; w1T[x] = w1[(size_t)u*80+m]; }
  float* w2T = ws + OFF_W2T;     // [256][256]
  for (long x = i; x < 256*256; x += stride){ int k = x>>8, u = x&255; w2T[x] = w2[(size_t)u*256+k]; }
}

// ---------------- prenet ----------------
__global__ __launch_bounds__(256) void k_prenet1(const float* __restrict__ di,
    const float* __restrict__ W1T, float* __restrict__ h1m, unsigned k10, unsigned k11){
  __shared__ float xs[NMEL];
  int bid = blockIdx.x;           // t*32 + b
  int t = bid >> 5, b = bid & 31;
  int tid = threadIdx.x;
  if (tid < NMEL) xs[tid] = (t == 0) ? 0.f : di[(size_t)b*40000 + (size_t)tid*500 + (t-1)];
  __syncthreads();
  float acc = 0.f;
  for (int m = 0; m < NMEL; ++m) acc += xs[m] * W1T[m*256 + tid];
  acc = fmaxf(acc, 0.f);
  unsigned idx = (unsigned)bid*256u + (unsigned)tid;
  h1m[(size_t)bid*256 + tid] = acc * mask_scale(k10, k11, idx);
}

__global__ __launch_bounds__(256) void k_prenet2(const float* __restrict__ h1m,
    const float* __restrict__ W2T, float* __restrict__ dec_ins, unsigned k20, unsigned k21){
  __shared__ float hs[PRE];
  int bid = blockIdx.x;
  int tid = threadIdx.x;
  hs[tid] = h1m[(size_t)bid*256 + tid];
  __syncthreads();
  float acc = 0.f;
  for (int k = 0; k < PRE; ++k) acc += hs[k] * W2T[k*256 + tid];
  acc = fmaxf(acc, 0.f);
  unsigned idx = (unsigned)bid*256u + (unsigned)tid;
  dec_ins[(size_t)bid*256 + tid] = acc * mask_scale(k20, k21, idx);
}

// ---------------- processed memory ----------------
__global__ __launch_bounds__(128) void k_procmem(const float* __restrict__ mem,
    const float* __restrict__ mWT, float* __restrict__ pm){
  __shared__ float ms[ENCD];
  int bid = blockIdx.x;  // b*300 + j
  int tid = threadIdx.x;
  const float* src = mem + (size_t)bid*ENCD;
  for (int i = tid; i < ENCD; i += 128) ms[i] = src[i];
  __syncthreads();
  float acc = 0.f;
  for (int k = 0; k < ENCD; ++k) acc += ms[k] * mWT[k*128 + tid];
  pm[(size_t)bid*128 + tid] = acc;
}

// ---------------- X source (CACHED loads; ring buffers make this safe) ----------------
__device__ __forceinline__ float2 xld2(const float* s0, int l0, const float* s1,
                                       const float* h, int b, int k){
  const float* p;
  if (k < l0) p = s0 + (size_t)b*l0 + k;
  else if (k < l0 + 512) p = s1 + (b<<9) + (k - l0);
  else p = h + (b<<10) + (k - (l0 + 512));
  return *(const float2*)p;
}

// ---------------- fused LSTM block: 512 thr, 8 waves, wave w owns rows 2w,2w+1 ----------------
__device__ __forceinline__ void lstm_block(int ub,
    const float* __restrict__ W1, const float* __restrict__ W2,
    const float* __restrict__ bih, const float* __restrict__ bhh,
    const float* __restrict__ s0, int l0, const float* __restrict__ s1,
    const float* __restrict__ hprev, int Ktot,
    float* __restrict__ c_st, float* __restrict__ hnew, int tid){
  __shared__ float Xc[2][128*32];       // [chunk k][b], XOR-swizzled slots
  __shared__ float gates[16][32];
  const int xw = l0 + 512, xw4 = xw >> 2;
  const int NC = Ktot >> 7;             // K chunks of 128 (14 att, 20 dec)
  const int w = tid >> 6, l = tid & 63;
  const int ss = l & 31, ph = l >> 5;   // ph = batch half
  const int rlA = 2*w, rlB = 2*w + 1;
  const int rowA = (rlA >> 2)*1024 + ub*4 + (rlA & 3);
  const int rowB = (rlB >> 2)*1024 + ub*4 + (rlB & 3);
  const float4* W1A = (const float4*)(W1 + (size_t)rowA*xw);
  const float4* W1B = (const float4*)(W1 + (size_t)rowB*xw);
  const float4* W2A = (const float4*)(W2 + ((size_t)rowA<<10));
  const float4* W2B = (const float4*)(W2 + ((size_t)rowB<<10));
  float accA[16] = {}, accB[16] = {};
  float2 sx[4];
  // stage chunk 0: 4096 floats / 512 thr = 4 float2 each
#pragma unroll
  for (int it = 0; it < 4; ++it){
    int pidx = tid + it*512;
    int b = pidx >> 6, kL = (pidx & 63)*2;
    sx[it] = xld2(s0, l0, s1, hprev, b, kL);
  }
#pragma unroll
  for (int it = 0; it < 4; ++it){
    int pidx = tid + it*512;
    int b = pidx >> 6, kL = (pidx & 63)*2;
    int a0 = kL*32 + (((b>>2) ^ ((kL>>2)&7))<<2) + (b&3);
    Xc[0][a0] = sx[it].x; Xc[0][a0+32] = sx[it].y;
  }
  float4 wA, wB;
  { int f = ss;
    wA = (f < xw4) ? W1A[f] : W2A[f - xw4];
    wB = (f < xw4) ? W1B[f] : W2B[f - xw4]; }
  __syncthreads();

  for (int c = 0; c < NC; ++c){
    float4 wAn, wBn;
    if (c + 1 < NC){
      int f = (c+1)*32 + ss;
      wAn = (f < xw4) ? W1A[f] : W2A[f - xw4];
      wBn = (f < xw4) ? W1B[f] : W2B[f - xw4];
      int kg0 = (c+1) << 7;
#pragma unroll
      for (int it = 0; it < 4; ++it){
        int pidx = tid + it*512;
        int b = pidx >> 6, kL = (pidx & 63)*2;
        sx[it] = xld2(s0, l0, s1, hprev, b, kg0 + kL);
      }
    }
    const float4* X4 = (const float4*)Xc[c & 1];
    const int sw = ss & 7;
#pragma unroll
    for (int e = 0; e < 4; ++e){
      int kL = 4*ss + e;
      float ea = (e==0)?wA.x:(e==1)?wA.y:(e==2)?wA.z:wA.w;
      float eb = (e==0)?wB.x:(e==1)?wB.y:(e==2)?wB.z:wB.w;
      int base = kL*8;
#pragma unroll
      for (int j = 0; j < 4; ++j){
        int g = ph*4 + j;
        float4 xv = X4[base + (g ^ sw)];
        accA[4*j+0] += ea*xv.x; accA[4*j+1] += ea*xv.y;
        accA[4*j+2] += ea*xv.z; accA[4*j+3] += ea*xv.w;
        accB[4*j+0] += eb*xv.x; accB[4*j+1] += eb*xv.y;
        accB[4*j+2] += eb*xv.z; accB[4*j+3] += eb*xv.w;
      }
    }
    if (c + 1 < NC){
#pragma unroll
      for (int it = 0; it < 4; ++it){
        int pidx = tid + it*512;
        int b = pidx >> 6, kL = (pidx & 63)*2;
        int a0 = kL*32 + (((b>>2) ^ ((kL>>2)&7))<<2) + (b&3);
        Xc[(c+1)&1][a0] = sx[it].x; Xc[(c+1)&1][a0+32] = sx[it].y;
      }
      wA = wAn; wB = wBn;
    }
    __syncthreads();
  }
  // cross-half pre-add (lanes ss and ss^16 of same ph cover disjoint k-slots)
#pragma unroll
  for (int j = 0; j < 16; ++j){
    accA[j] += __shfl_xor(accA[j], 16, 64);
    accB[j] += __shfl_xor(accB[j], 16, 64);
  }
  // reduce-scatter 16 values over 16-lane groups: lane ends with b-off = ss&15
#pragma unroll
  for (int m = 8; m >= 1; m >>= 1){
    int up = ss & m;
#pragma unroll
    for (int j = 0; j < m; ++j){
      float sA = up ? accA[j] : accA[j+m];
      float kA = up ? accA[j+m] : accA[j];
      float sB = up ? accB[j] : accB[j+m];
      float kB = up ? accB[j+m] : accB[j];
      accA[j] = kA + __shfl_xor(sA, m, 64);
      accB[j] = kB + __shfl_xor(sB, m, 64);
    }
  }
  if (!(l & 16)){
    int b = ph*16 + (l & 15);
    gates[rlA][b] = accA[0];
    gates[rlB][b] = accB[0];
  }
  __syncthreads();
  if (tid < 128){
    int b = tid & 31, u = tid >> 5;
    int gu = ub*4 + u;
    float gi = gates[u][b]     + bih[gu]         + bhh[gu];
    float gf = gates[4+u][b]   + bih[1024+gu]    + bhh[1024+gu];
    float gg = gates[8+u][b]   + bih[2048+gu]    + bhh[2048+gu];
    float go = gates[12+u][b]  + bih[3072+gu]    + bhh[3072+gu];
    float ii = 1.f/(1.f + expf(-gi));
    float ff = 1.f/(1.f + expf(-gf));
    float oo = 1.f/(1.f + expf(-go));
    float tg = tanhf(gg);
    float cold = gload(&c_st[b*1024 + gu]);
    float cn = ff*cold + ii*tg;
    gstore(&c_st[b*1024 + gu], cn);
    gstore(&hnew[b*1024 + gu], oo*tanhf(cn));
  }
  __syncthreads();
}

// ---------------- energy tile (two 256-thr halves work two tiles) ----------------
__device__ __forceinline__ void energy_tile(int b, int tile, bool act, int h,
    const float* __restrict__ aw, const float* __restrict__ awc,
    const float* __restrict__ lcW, const float* __restrict__ ldW, const float* __restrict__ vw,
    const float* __restrict__ sPq, const float* __restrict__ pm, float* __restrict__ e_ws, int t2){
  __shared__ float sIn[2][2][46];
  __shared__ float cfs[2][16][33];
  __shared__ float ep[2][16][17];
  int j0 = tile*16;
  if (act){
    if (t2 < 46){ int j = j0 - 15 + t2; sIn[h][0][t2] = (j >= 0 && j < 300) ? gload(&aw[b*300 + j]) : 0.f; }
    else if (t2 < 92){ int i = t2 - 46; int j = j0 - 15 + i; sIn[h][1][i] = (j >= 0 && j < 300) ? gload(&awc[b*300 + j]) : 0.f; }
  }
  __syncthreads();
  if (act){
    int fg = t2 & 15, jl = t2 >> 4;
    int f0 = 2*fg;
    float c0 = 0.f, c1 = 0.f;
#pragma unroll
    for (int c = 0; c < 2; ++c)
#pragma unroll
      for (int k = 0; k < 31; ++k){
        float a = sIn[h][c][jl + k];
        c0 += a * lcW[f0*62 + c*31 + k];
        c1 += a * lcW[(f0+1)*62 + c*31 + k];
      }
    cfs[h][jl][f0] = c0; cfs[h][jl][f0+1] = c1;
  }
  __syncthreads();
  if (act){
    int dg = t2 & 15, jl = t2 >> 4;
    int j = j0 + jl;
    float s = 0.f;
    if (j < 300){
      const float* pmrow = pm + ((size_t)(b*300 + j))*128 + dg*8;
#pragma unroll
      for (int dd = 0; dd < 8; ++dd){
        int d = dg*8 + dd;
        float acc = sPq[d] + pmrow[dd];
#pragma unroll
        for (int f = 0; f < 32; ++f) acc += cfs[h][jl][f] * ldW[d*32 + f];
        s += vw[d] * tanhf(acc);
      }
    }
    ep[h][jl][dg] = s;
  }
  __syncthreads();
  if (act && t2 < 16){
    int j = j0 + t2;
    if (j < 300){
      float s = 0.f;
#pragma unroll
      for (int dg = 0; dg < 16; ++dg) s += ep[h][t2][dg];
      gstore(&e_ws[b*300 + j], s);
    }
  }
  __syncthreads();
}

// ---------------- B: pq (4-seg) + energy (2 halves x 2 rounds) ----------------
__device__ __forceinline__ void pq_energy(int b, int jt, const float* __restrict__ ah,
    const float* __restrict__ qWT, const float* __restrict__ aw, const float* __restrict__ awc,
    const float* __restrict__ lcW, const float* __restrict__ ldW, const float* __restrict__ vw,
    const float* __restrict__ pm, float* __restrict__ e_ws, int tid){
  __shared__ float sAh[1024];
  __shared__ float pqs[512];
  __shared__ float sPq[128];
  for (int i = tid; i < 1024; i += 512) sAh[i] = ah[b*1024 + i];   // cached (ring slot)
  __syncthreads();
  int d = tid & 127, seg = tid >> 7;   // 4 u-segments of 256
  const float* qt = qWT + (size_t)(seg*256)*128 + d;
  const float* sh = sAh + seg*256;
  float a0 = 0.f, a1 = 0.f, a2 = 0.f, a3 = 0.f;
  for (int u = 0; u < 256; u += 4){
    a0 += sh[u]   * qt[(size_t)u*128];
    a1 += sh[u+1] * qt[(size_t)(u+1)*128];
    a2 += sh[u+2] * qt[(size_t)(u+2)*128];
    a3 += sh[u+3] * qt[(size_t)(u+3)*128];
  }
  pqs[seg*128 + d] = (a0 + a1) + (a2 + a3);
  __syncthreads();
  if (tid < 128) sPq[tid] = (pqs[tid] + pqs[128+tid]) + (pqs[256+tid] + pqs[384+tid]);
  __syncthreads();
  int h = tid >> 8, t2 = tid & 255;
  for (int r = 0; r < 2; ++r){
    int tile = r*16 + jt*2 + h;
    energy_tile(b, tile, tile < 19, h, aw, awc, lcW, ldW, vw, sPq, pm, e_ws, t2);
  }
}

// ---------------- distributed dec output slice: block (b,jt) does 10 mel cols ----------------
__device__ __forceinline__ void dec_out_slice(int b, int jt,
    const float* __restrict__ dh, const float* __restrict__ ctx,
    const float* __restrict__ pWT, const float* __restrict__ projb,
    const float* __restrict__ gateW, const float* __restrict__ gateb,
    float* __restrict__ out, int s, int tid){
  __shared__ float sX[1536];
  __shared__ float melp[48][11];
  __shared__ float gatep[32];
  for (int i = tid; i < 1024; i += 512) sX[i] = dh[b*1024 + i];     // cached (ring slot)
  if (tid < 512) { int i = tid; sX[1024 + i] = ctx[b*512 + i]; }    // cached (ring slot)
  __syncthreads();
  if (tid < 480){
    int mi = tid % 10, kseg = tid / 10;     // 48 k-segments of 32
    int m = jt*10 + mi;
    const float* pw = pWT + m;
    int k0 = kseg*32;
    float a0 = 0.f, a1 = 0.f;
#pragma unroll 8
    for (int k = 0; k < 32; k += 2){
      a0 += sX[k0+k]   * pw[(size_t)(k0+k)*80];
      a1 += sX[k0+k+1] * pw[(size_t)(k0+k+1)*80];
    }
    melp[kseg][mi] = a0 + a1;
  } else if (jt == 0){
    int kseg = tid - 480;                    // 32 segs of 48
    int k0 = kseg*48;
    float a = 0.f;
    for (int k = 0; k < 48; ++k) a += sX[k0+k] * gateW[k0+k];
    gatep[kseg] = a;
  }
  __syncthreads();
  if (tid < 10){
    float s2 = projb[jt*10 + tid];
    for (int q = 0; q < 48; ++q) s2 += melp[q][tid];
    out[(size_t)b*40000 + (size_t)(jt*10 + tid)*500 + s] = s2;
  }
  if (jt == 0 && tid == 10){
    float s2 = gateb[0];
    for (int q = 0; q < 32; ++q) s2 += gatep[q];
    out[1280000 + (size_t)b*500 + s] = s2;
  }
  __syncthreads();
}

// ---------------- C: softmax + ctx (8-way d-split, 512 thr) ----------------
__device__ __forceinline__ void soft_phase(int b, int dsl, const float* __restrict__ e_ws,
    const int* __restrict__ lens, const float* __restrict__ mem,
    float* __restrict__ aw, float* __restrict__ awc, float* __restrict__ ctx,
    float* __restrict__ out, int t, int tid){
  __shared__ float se[300];
  __shared__ float sa[300];
  __shared__ float red[512];
  int len = lens[b];
  for (int j = tid; j < 300; j += 512) se[j] = gload(&e_ws[b*300 + j]);
  __syncthreads();
  float m = -1e30f;
  for (int j = tid; j < len; j += 512) m = fmaxf(m, se[j]);
  red[tid] = m; __syncthreads();
  for (int s = 256; s > 0; s >>= 1){ if (tid < s) red[tid] = fmaxf(red[tid], red[tid + s]); __syncthreads(); }
  float mx = red[0]; __syncthreads();
  float ssum = 0.f;
  for (int j = tid; j < len; j += 512) ssum += expf(se[j] - mx);
  red[tid] = ssum; __syncthreads();
  for (int s = 256; s > 0; s >>= 1){ if (tid < s) red[tid] += red[tid + s]; __syncthreads(); }
  float inv = 1.f/red[0];
  __syncthreads();
  float* al = out + 1296000 + (size_t)b*150000 + (size_t)t*300;
  for (int j = tid; j < 300; j += 512){
    float v = (j < len) ? expf(se[j] - mx)*inv : 0.f;
    sa[j] = v;
    if (dsl == 0){
      gstore(&aw[b*300 + j], v);
      gstore(&awc[b*300 + j], gload(&awc[b*300 + j]) + v);
      al[j] = v;
    }
  }
  __syncthreads();
  int d = dsl*64 + (tid & 63), jq = tid >> 6;   // 8-way j-split
  int chunk = (len + 7) >> 3;
  int j0 = jq*chunk, j1 = min(len, j0 + chunk);
  float a0 = 0.f, a1 = 0.f;
  const float* mb = mem + (size_t)b*153600 + d;
  int j = j0;
  for (; j + 1 < j1; j += 2){
    a0 += sa[j]   * mb[(size_t)j*512];
    a1 += sa[j+1] * mb[(size_t)(j+1)*512];
  }
  if (j < j1) a0 += sa[j]*mb[(size_t)j*512];
  red[tid] = a0 + a1; __syncthreads();
  if (jq == 0){
    int ln = tid & 63;
    float s = 0.f;
#pragma unroll
    for (int q = 0; q < 8; ++q) s += red[ln + 64*q];
    gstore(&ctx[b*512 + d], s);
  }
  __syncthreads();
}

// ---------------- persistent loop ----------------
struct DecParams {
  const float *memory;
  const int   *lens;
  const float *attWih, *attWhh, *attBih, *attBhh;
  const float *decWih, *decWhh, *decBih, *decBhh;
  const float *lcW, *ldW, *vw, *projb, *gateW, *gateb;
  float *ws, *out;
};

__global__ void __launch_bounds__(512, 2) k_loop(DecParams p){
  int wg = blockIdx.x, tid = threadIdx.x;
  float* ws = p.ws;
  float* decins = ws + OFF_DECINS;
  float* e_ws = ws + OFF_E;
  float* pm = ws + OFF_PM;
  float* AC = ws + OFF_AC;
  float* DC = ws + OFF_DC;
  float* aw = ws + OFF_AW;
  float* awc = ws + OFF_AWC;
  float* qWT = ws + OFF_QWT;
  float* pWT = ws + OFF_PROJWT;
  unsigned* slots = (unsigned*)(ws + OFF_SLOTS);
  unsigned ep = 0;
  int b = wg >> 3, jt = wg & 7;

#define AHR(s) (ws + OFF_AHR + (size_t)(s)*32768)
#define DHR(s) (ws + OFF_DHR + (size_t)(s)*32768)
#define CXR(s) (ws + OFF_CXR + (size_t)(s)*16384)

  // prologue: zero all ring slots at the coherence point (write-through)
  for (unsigned i = (unsigned)wg*512u + tid; i < (unsigned)RINGS_N; i += 131072u)
    gstore(ws + OFF_AHR + i, 0.f);
  gbar(slots, ++ep);

  // A(0): ah(0) = LSTM([x_0, ctx=0], h=0) -> AHR(1)
  lstm_block(wg, p.attWih, p.attWhh, p.attBih, p.attBhh,
             decins, PRE, CXR(0), AHR(0), 1792, AC, AHR(1), tid);
  gbar(slots, ++ep);

  for (int t = 0; t < TDEC; ++t){
    int cu = (t + 1) % RD, pr = t % RD, nx = (t + 2) % RD;
    // B~: pq + energy; distributed dec-out of step t-1
    pq_energy(b, jt, AHR(cu), qWT, aw, awc, p.lcW, p.ldW, p.vw, pm, e_ws, tid);
    if (t > 0)
      dec_out_slice(b, jt, DHR(pr), CXR(pr), pWT, p.projb, p.gateW, p.gateb, p.out, t - 1, tid);
    gbar(slots, ++ep);
    // C: softmax + ctx
    soft_phase(b, jt, e_ws, p.lens, p.memory, aw, awc, CXR(cu), p.out, t, tid);
    gbar(slots, ++ep);
    // D~: dec LSTM + att LSTM (t+1)
    lstm_block(wg, p.decWih, p.decWhh, p.decBih, p.decBhh,
               AHR(cu), 1024, CXR(cu), DHR(pr), 2560, DC, DHR(cu), tid);
    if (t + 1 < TDEC)
      lstm_block(wg, p.attWih, p.attWhh, p.attBih, p.attBhh,
                 decins + (size_t)(t + 1)*NB*PRE, PRE, CXR(cu), AHR(cu), 1792,
                 AC, AHR(nx), tid);
    gbar(slots, ++ep);
  }
  // epilogue: dec-out of final step (t=499): dh/ctx in slots (500%8)=4
  dec_out_slice(b, jt, DHR(500 % RD), CXR(500 % RD), pWT, p.projb, p.gateW, p.gateb,
                p.out, TDEC - 1, tid);
#undef AHR
#undef DHR
#undef CXR
}

// ---------------- host ----------------
extern "C" void kernel_launch(void* const* d_in, const int* in_sizes, int n_in,
                              void* d_out, int out_size, void* d_ws, size_t ws_size,
                              hipStream_t stream) {
  const float* memory   = (const float*)d_in[0];
  const float* dec_in   = (const float*)d_in[1];
  const int*   lens     = (const int*)  d_in[2];
  const float* pre_W1   = (const float*)d_in[3];
  const float* pre_W2   = (const float*)d_in[4];
  const float* att_Wih  = (const float*)d_in[5];
  const float* att_Whh  = (const float*)d_in[6];
  const float* att_bih  = (const float*)d_in[7];
  const float* att_bhh  = (const float*)d_in[8];
  const float* q_W      = (const float*)d_in[9];
  const float* m_W      = (const float*)d_in[10];
  const float* v_w      = (const float*)d_in[11];
  const float* lc_W     = (const float*)d_in[12];
  const float* ld_W     = (const float*)d_in[13];
  const float* dec_Wih  = (const float*)d_in[14];
  const float* dec_Whh  = (const float*)d_in[15];
  const float* dec_bih  = (const float*)d_in[16];
  const float* dec_bhh  = (const float*)d_in[17];
  const float* proj_W   = (const float*)d_in[18];
  const float* proj_b   = (const float*)d_in[19];
  const float* gate_W   = (const float*)d_in[20];
  const float* gate_b   = (const float*)d_in[21];
  float* out = (float*)d_out;
  float* ws  = (float*)d_ws;

  // Partitionable (foldlike) split of jax.random.key(1)
  unsigned k10, k11, k20, k21;
  tf2x32(0u, 1u, 0u, 0u, k10, k11);
  tf2x32(0u, 1u, 0u, 1u, k20, k21);

  k_setup<<<1024, 256, 0, stream>>>(ws, q_W, proj_W, m_W, pre_W1, pre_W2);
  k_prenet1<<<TDEC*NB, 256, 0, stream>>>(dec_in, ws + OFF_W1T, ws + OFF_H1M, k10, k11);
  k_prenet2<<<TDEC*NB, 256, 0, stream>>>(ws + OFF_H1M, ws + OFF_W2T, ws + OFF_DECINS, k20, k21);
  k_procmem<<<NB*TENC, 128, 0, stream>>>(memory, ws + OFF_MWT, ws + OFF_PM);

  DecParams hp;
  hp.memory = memory; hp.lens = lens;
  hp.attWih = att_Wih; hp.attWhh = att_Whh; hp.attBih = att_bih; hp.attBhh = att_bhh;
  hp.decWih = dec_Wih; hp.decWhh = dec_Whh; hp.decBih = dec_bih; hp.decBhh = dec_bhh;
  hp.lcW = lc_W; hp.ldW = ld_W; hp.vw = v_w; hp.projb = proj_b; hp.gateW = gate_W; hp.gateb = gate_b;
  hp.ws = ws; hp.out = out;
  k_loop<<<256, 512, 0, stream>>>(hp);
}

// Round 14
// 76415.179 us; speedup vs baseline: 1.1331x; 1.1331x over previous
//
#include <hip/hip_runtime.h>

#define NB 32
#define TENC 300
#define TDEC 500
#define NMEL 80
#define ENCD 512
#define PRE 256
#define ADIM 128
#define RD 4          // ring depth
#define WSPLIT 2944   // dec bf16 rows 0..2943 in LO region, 2944..4095 in HI

// ---------------- workspace layout (float offsets) ----------------
#define OFF_DECINS 0ull                         // u16[4,096,000] = 2,048,000 floats (bf16 decins)
#define OFF_WHI    2048000ull                   // u16[1152*2560=2,949,120] = 1,474,560 floats
#define OFF_AHR    4096000ull                   // 4*32768 = 131,072
#define OFF_DHR    (OFF_AHR + 131072ull)        // 131,072
#define OFF_CXR    (OFF_DHR + 131072ull)        // 4*16384 = 65,536
#define RINGS_N    327680ull
#define OFF_WLO    (OFF_AHR + RINGS_N)          // 4,423,680: u16[2944*2560=7,536,640] = 3,768,320 fl -> ends 8,192,000
#define OFF_PM     8192000ull                   // 32*300*128 = 1,228,800
#define OFF_STATE  (OFF_PM + 1228800ull)        // = 9,420,800
#define OFF_AC     (OFF_STATE + 0ull)           // 32,768
#define OFF_DC     (OFF_STATE + 32768ull)       // 32,768
#define OFF_AW     (OFF_STATE + 65536ull)       // 9,600
#define OFF_AWC    (OFF_STATE + 75136ull)       // 9,600
#define OFF_E      (OFF_STATE + 84736ull)       // 9,600
#define OFF_SLOTS  (OFF_STATE + 94336ull)       // 256 u32 slots (contiguous)
#define STATE_N    98440ull
#define OFF_QWT    (OFF_STATE + STATE_N)        // 131,072
#define OFF_PROJWT (OFF_QWT + 131072ull)        // 122,880
#define OFF_MWT    (OFF_PROJWT + 122880ull)     // 65,536
#define OFF_W1T    (OFF_MWT + 65536ull)         // 20,480
#define OFF_W2T    (OFF_W1T + 20480ull)         // 65,536

// ---------------- bf16 helpers ----------------
__device__ __forceinline__ unsigned short f2bf(float f){
  unsigned u = __float_as_uint(f);
  unsigned r = (u + 0x7FFFu + ((u >> 16) & 1u)) >> 16;   // RNE
  return (unsigned short)r;
}
__device__ __forceinline__ float bf2f(unsigned short h){
  return __uint_as_float(((unsigned)h) << 16);
}

// ---------------- device-coherent (agent-scope, fence-free) helpers ----------------
__device__ __forceinline__ float gload(const float* p){
  return __hip_atomic_load(p, __ATOMIC_RELAXED, __HIP_MEMORY_SCOPE_AGENT);
}
__device__ __forceinline__ void gstore(float* p, float v){
  __hip_atomic_store(p, v, __ATOMIC_RELAXED, __HIP_MEMORY_SCOPE_AGENT);
}

// ---------------- flat hot-spin grid barrier (round-10 proven) ----------------
__device__ __forceinline__ void gbar(unsigned* slots, unsigned epoch){
  __syncthreads();
  int tid = threadIdx.x;
  if (tid == 0)
    __hip_atomic_store(&slots[blockIdx.x], epoch, __ATOMIC_RELAXED, __HIP_MEMORY_SCOPE_AGENT);
  if (tid < 64){
    const unsigned long long* p = (const unsigned long long*)slots;
    unsigned long long a, b;
    do {
      a = __hip_atomic_load(p + 2*tid,     __ATOMIC_RELAXED, __HIP_MEMORY_SCOPE_AGENT);
      b = __hip_atomic_load(p + 2*tid + 1, __ATOMIC_RELAXED, __HIP_MEMORY_SCOPE_AGENT);
    } while ((unsigned)a < epoch || (unsigned)(a >> 32) < epoch ||
             (unsigned)b < epoch || (unsigned)(b >> 32) < epoch);
  }
  __syncthreads();
}

// ---------------- threefry2x32 (matches JAX bit-exactly) ----------------
__host__ __device__ __forceinline__ unsigned rotl32(unsigned v, int r){ return (v<<r)|(v>>(32-r)); }

__host__ __device__ __forceinline__ void tf2x32(unsigned k0, unsigned k1, unsigned c0, unsigned c1,
                                                unsigned& y0, unsigned& y1){
  unsigned ks2 = k0 ^ k1 ^ 0x1BD11BDAu;
  unsigned x0 = c0 + k0, x1 = c1 + k1;
#define TFR(r) x0 += x1; x1 = rotl32(x1, r); x1 ^= x0;
  TFR(13) TFR(15) TFR(26) TFR(6)
  x0 += k1;  x1 += ks2 + 1u;
  TFR(17) TFR(29) TFR(16) TFR(24)
  x0 += ks2; x1 += k0 + 2u;
  TFR(13) TFR(15) TFR(26) TFR(6)
  x0 += k0;  x1 += k1 + 3u;
  TFR(17) TFR(29) TFR(16) TFR(24)
  x0 += k1;  x1 += ks2 + 4u;
  TFR(13) TFR(15) TFR(26) TFR(6)
  x0 += ks2; x1 += k0 + 5u;
#undef TFR
  y0 = x0; y1 = x1;
}

__device__ __forceinline__ float mask_scale(unsigned k0, unsigned k1, unsigned idx){
  unsigned y0, y1;
  tf2x32(k0, k1, 0u, idx, y0, y1);
  unsigned bits = y0 ^ y1;
  float u = __uint_as_float((bits >> 9) | 0x3f800000u) - 1.0f;
  return (u < 0.9f) ? (1.0f/0.9f) : 0.0f;
}

// ---------------- setup: zero state, transposes, dec-weight bf16 pack ----------------
__global__ __launch_bounds__(256) void k_setup(float* __restrict__ ws,
    const float* __restrict__ qW, const float* __restrict__ projW, const float* __restrict__ mW,
    const float* __restrict__ w1, const float* __restrict__ w2,
    const float* __restrict__ dWih, const float* __restrict__ dWhh){
  long i = (long)blockIdx.x*256 + threadIdx.x;
  long stride = (long)gridDim.x*256;
  float* st = ws + OFF_STATE;
  for (long x = i; x < (long)STATE_N; x += stride) st[x] = 0.f;
  float* qWT = ws + OFF_QWT;     // [1024][128]
  for (long x = i; x < 1024*128; x += stride){ int u = x>>7, d = x&127; qWT[x] = qW[(size_t)d*1024+u]; }
  float* pWT = ws + OFF_PROJWT;  // [1536][80]
  for (long x = i; x < 1536*80; x += stride){ int k = x/80, m = x%80; pWT[x] = projW[(size_t)m*1536+k]; }
  float* mWT = ws + OFF_MWT;     // [512][128]
  for (long x = i; x < 512*128; x += stride){ int k = x>>7, d = x&127; mWT[x] = mW[(size_t)d*512+k]; }
  float* w1T = ws + OFF_W1T;     // [80][256]
  for (long x = i; x < 80*256; x += stride){ int m = x>>8, u = x&255; w1T[x] = w1[(size_t)u*80+m]; }
  float* w2T = ws + OFF_W2T;     // [256][256]
  for (long x = i; x < 256*256; x += stride){ int k = x>>8, u = x&255; w2T[x] = w2[(size_t)u*256+k]; }
  // dec weights -> bf16, rows concatenated [Wih(1536) | Whh(1024)] = 2560 cols
  unsigned short* wlo = (unsigned short*)(ws + OFF_WLO);
  for (long x = i; x < (long)WSPLIT*2560; x += stride){
    int row = (int)(x/2560), c = (int)(x%2560);
    float v = (c < 1536) ? dWih[(size_t)row*1536 + c] : dWhh[(size_t)row*1024 + (c-1536)];
    wlo[x] = f2bf(v);
  }
  unsigned short* whi = (unsigned short*)(ws + OFF_WHI);
  for (long x = i; x < (long)(4096-WSPLIT)*2560; x += stride){
    int row = WSPLIT + (int)(x/2560), c = (int)(x%2560);
    float v = (c < 1536) ? dWih[(size_t)row*1536 + c] : dWhh[(size_t)row*1024 + (c-1536)];
    whi[x] = f2bf(v);
  }
}

// ---------------- fused prenet (layer1 + dropout + layer2 + dropout -> bf16 decins) ----------------
__global__ __launch_bounds__(256) void k_prenet(const float* __restrict__ di,
    const float* __restrict__ W1T, const float* __restrict__ W2T,
    unsigned short* __restrict__ dec_ins,
    unsigned k10, unsigned k11, unsigned k20, unsigned k21){
  __shared__ float xs[NMEL];
  __shared__ float h1s[PRE];
  int bid = blockIdx.x;           // t*32 + b
  int t = bid >> 5, b = bid & 31;
  int tid = threadIdx.x;
  if (tid < NMEL) xs[tid] = (t == 0) ? 0.f : di[(size_t)b*40000 + (size_t)tid*500 + (t-1)];
  __syncthreads();
  float acc = 0.f;
  for (int m = 0; m < NMEL; ++m) acc += xs[m] * W1T[m*256 + tid];
  acc = fmaxf(acc, 0.f);
  unsigned idx = (unsigned)bid*256u + (unsigned)tid;
  h1s[tid] = acc * mask_scale(k10, k11, idx);
  __syncthreads();
  float a2 = 0.f;
  for (int k = 0; k < PRE; ++k) a2 += h1s[k] * W2T[k*256 + tid];
  a2 = fmaxf(a2, 0.f);
  a2 *= mask_scale(k20, k21, idx);
  dec_ins[(size_t)bid*256 + tid] = f2bf(a2);
}

// ---------------- processed memory ----------------
__global__ __launch_bounds__(128) void k_procmem(const float* __restrict__ mem,
    const float* __restrict__ mWT, float* __restrict__ pm){
  __shared__ float ms[ENCD];
  int bid = blockIdx.x;  // b*300 + j
  int tid = threadIdx.x;
  const float* src = mem + (size_t)bid*ENCD;
  for (int i = tid; i < ENCD; i += 128) ms[i] = src[i];
  __syncthreads();
  float acc = 0.f;
  for (int k = 0; k < ENCD; ++k) acc += ms[k] * mWT[k*128 + tid];
  pm[(size_t)bid*128 + tid] = acc;
}

// ---------------- X source (cached; S0B = s0 stored as bf16) ----------------
template<bool S0B>
__device__ __forceinline__ float2 xld2(const void* s0v, int l0, const float* s1,
                                       const float* h, int b, int k){
  if (k < l0){
    if constexpr (S0B){
      const unsigned short* s0 = (const unsigned short*)s0v;
      unsigned u = *(const unsigned*)(s0 + (size_t)b*l0 + k);
      float2 r; r.x = __uint_as_float((u & 0xFFFFu) << 16); r.y = __uint_as_float((u >> 16) << 16);
      return r;
    } else {
      const float* s0 = (const float*)s0v;
      return *(const float2*)(s0 + (size_t)b*l0 + k);
    }
  }
  if (k < l0 + 512) return *(const float2*)(s1 + (b<<9) + (k - l0));
  return *(const float2*)(h + (b<<10) + (k - (l0 + 512)));
}

// ---------------- fused LSTM block: 512 thr, 8 waves, wave w owns rows 2w,2w+1 ----------------
// WB: weights are bf16 (concatenated rows, split LO/HI).  S0B: s0 is bf16.
template<bool S0B, bool WB>
__device__ __forceinline__ void lstm_block(int ub,
    const float* __restrict__ W1, const float* __restrict__ W2,
    const unsigned short* __restrict__ wlo, const unsigned short* __restrict__ whi,
    const float* __restrict__ bih, const float* __restrict__ bhh,
    const void* __restrict__ s0, int l0, const float* __restrict__ s1,
    const float* __restrict__ hprev, int Ktot,
    float* __restrict__ c_st, float* __restrict__ hnew, int tid){
  __shared__ float Xc[2][128*32];       // [chunk k][b], XOR-swizzled slots
  __shared__ float gates[16][32];
  const int xw = l0 + 512, xw4 = xw >> 2;
  const int NC = Ktot >> 7;             // K chunks of 128 (14 att, 20 dec)
  const int w = tid >> 6, l = tid & 63;
  const int ss = l & 31, ph = l >> 5;   // ph = batch half
  const int rlA = 2*w, rlB = 2*w + 1;
  const int rowA = (rlA >> 2)*1024 + ub*4 + (rlA & 3);
  const int rowB = (rlB >> 2)*1024 + ub*4 + (rlB & 3);
  // fp32 row pointers
  const float4* W1A = (const float4*)(W1 + (size_t)rowA*xw);
  const float4* W1B = (const float4*)(W1 + (size_t)rowB*xw);
  const float4* W2A = (const float4*)(W2 + ((size_t)rowA<<10));
  const float4* W2B = (const float4*)(W2 + ((size_t)rowB<<10));
  // bf16 row pointers (concatenated 2560-col rows)
  const unsigned short* BA = nullptr; const unsigned short* BB = nullptr;
  if constexpr (WB){
    BA = (rowA < WSPLIT) ? wlo + (size_t)rowA*2560 : whi + (size_t)(rowA - WSPLIT)*2560;
    BB = (rowB < WSPLIT) ? wlo + (size_t)rowB*2560 : whi + (size_t)(rowB - WSPLIT)*2560;
  }
  auto loadWA = [&](int f)->float4{
    if constexpr (WB){
      ushort4 h4 = *(const ushort4*)(BA + 4*(size_t)f);
      return make_float4(bf2f(h4.x), bf2f(h4.y), bf2f(h4.z), bf2f(h4.w));
    } else return (f < xw4) ? W1A[f] : W2A[f - xw4];
  };
  auto loadWB = [&](int f)->float4{
    if constexpr (WB){
      ushort4 h4 = *(const ushort4*)(BB + 4*(size_t)f);
      return make_float4(bf2f(h4.x), bf2f(h4.y), bf2f(h4.z), bf2f(h4.w));
    } else return (f < xw4) ? W1B[f] : W2B[f - xw4];
  };
  float accA[16] = {}, accB[16] = {};
  float2 sx[4];
  // stage chunk 0: 4096 floats / 512 thr = 4 float2 each
#pragma unroll
  for (int it = 0; it < 4; ++it){
    int pidx = tid + it*512;
    int b = pidx >> 6, kL = (pidx & 63)*2;
    sx[it] = xld2<S0B>(s0, l0, s1, hprev, b, kL);
  }
#pragma unroll
  for (int it = 0; it < 4; ++it){
    int pidx = tid + it*512;
    int b = pidx >> 6, kL = (pidx & 63)*2;
    int a0 = kL*32 + (((b>>2) ^ ((kL>>2)&7))<<2) + (b&3);
    Xc[0][a0] = sx[it].x; Xc[0][a0+32] = sx[it].y;
  }
  float4 wA = loadWA(ss), wB = loadWB(ss);
  __syncthreads();

  for (int c = 0; c < NC; ++c){
    float4 wAn, wBn;
    if (c + 1 < NC){
      int f = (c+1)*32 + ss;
      wAn = loadWA(f); wBn = loadWB(f);
      int kg0 = (c+1) << 7;
#pragma unroll
      for (int it = 0; it < 4; ++it){
        int pidx = tid + it*512;
        int b = pidx >> 6, kL = (pidx & 63)*2;
        sx[it] = xld2<S0B>(s0, l0, s1, hprev, b, kg0 + kL);
      }
    }
    const float4* X4 = (const float4*)Xc[c & 1];
    const int sw = ss & 7;
#pragma unroll
    for (int e = 0; e < 4; ++e){
      int kL = 4*ss + e;
      float ea = (e==0)?wA.x:(e==1)?wA.y:(e==2)?wA.z:wA.w;
      float eb = (e==0)?wB.x:(e==1)?wB.y:(e==2)?wB.z:wB.w;
      int base = kL*8;
#pragma unroll
      for (int j = 0; j < 4; ++j){
        int g = ph*4 + j;
        float4 xv = X4[base + (g ^ sw)];
        accA[4*j+0] += ea*xv.x; accA[4*j+1] += ea*xv.y;
        accA[4*j+2] += ea*xv.z; accA[4*j+3] += ea*xv.w;
        accB[4*j+0] += eb*xv.x; accB[4*j+1] += eb*xv.y;
        accB[4*j+2] += eb*xv.z; accB[4*j+3] += eb*xv.w;
      }
    }
    if (c + 1 < NC){
#pragma unroll
      for (int it = 0; it < 4; ++it){
        int pidx = tid + it*512;
        int b = pidx >> 6, kL = (pidx & 63)*2;
        int a0 = kL*32 + (((b>>2) ^ ((kL>>2)&7))<<2) + (b&3);
        Xc[(c+1)&1][a0] = sx[it].x; Xc[(c+1)&1][a0+32] = sx[it].y;
      }
      wA = wAn; wB = wBn;
    }
    __syncthreads();
  }
  // cross-half pre-add (lanes ss and ss^16 of same ph cover disjoint k-slots)
#pragma unroll
  for (int j = 0; j < 16; ++j){
    accA[j] += __shfl_xor(accA[j], 16, 64);
    accB[j] += __shfl_xor(accB[j], 16, 64);
  }
  // reduce-scatter 16 values over 16-lane groups
#pragma unroll
  for (int m = 8; m >= 1; m >>= 1){
    int up = ss & m;
#pragma unroll
    for (int j = 0; j < m; ++j){
      float sA = up ? accA[j] : accA[j+m];
      float kA = up ? accA[j+m] : accA[j];
      float sB = up ? accB[j] : accB[j+m];
      float kB = up ? accB[j+m] : accB[j];
      accA[j] = kA + __shfl_xor(sA, m, 64);
      accB[j] = kB + __shfl_xor(sB, m, 64);
    }
  }
  if (!(l & 16)){
    int b = ph*16 + (l & 15);
    gates[rlA][b] = accA[0];
    gates[rlB][b] = accB[0];
  }
  __syncthreads();
  if (tid < 128){
    int b = tid & 31, u = tid >> 5;
    int gu = ub*4 + u;
    float gi = gates[u][b]     + bih[gu]         + bhh[gu];
    float gf = gates[4+u][b]   + bih[1024+gu]    + bhh[1024+gu];
    float gg = gates[8+u][b]   + bih[2048+gu]    + bhh[2048+gu];
    float go = gates[12+u][b]  + bih[3072+gu]    + bhh[3072+gu];
    float ii = 1.f/(1.f + expf(-gi));
    float ff = 1.f/(1.f + expf(-gf));
    float oo = 1.f/(1.f + expf(-go));
    float tg = tanhf(gg);
    float cold = gload(&c_st[b*1024 + gu]);
    float cn = ff*cold + ii*tg;
    gstore(&c_st[b*1024 + gu], cn);
    gstore(&hnew[b*1024 + gu], oo*tanhf(cn));
  }
  __syncthreads();
}

// ---------------- energy tile (two 256-thr halves work two tiles) ----------------
__device__ __forceinline__ void energy_tile(int b, int tile, bool act, int h,
    const float* __restrict__ aw, const float* __restrict__ awc,
    const float* __restrict__ lcW, const float* __restrict__ ldW, const float* __restrict__ vw,
    const float* __restrict__ sPq, const float* __restrict__ pm, float* __restrict__ e_ws, int t2){
  __shared__ float sIn[2][2][46];
  __shared__ float cfs[2][16][33];
  __shared__ float ep[2][16][17];
  int j0 = tile*16;
  if (act){
    if (t2 < 46){ int j = j0 - 15 + t2; sIn[h][0][t2] = (j >= 0 && j < 300) ? gload(&aw[b*300 + j]) : 0.f; }
    else if (t2 < 92){ int i = t2 - 46; int j = j0 - 15 + i; sIn[h][1][i] = (j >= 0 && j < 300) ? gload(&awc[b*300 + j]) : 0.f; }
  }
  __syncthreads();
  if (act){
    int fg = t2 & 15, jl = t2 >> 4;
    int f0 = 2*fg;
    float c0 = 0.f, c1 = 0.f;
#pragma unroll
    for (int c = 0; c < 2; ++c)
#pragma unroll
      for (int k = 0; k < 31; ++k){
        float a = sIn[h][c][jl + k];
        c0 += a * lcW[f0*62 + c*31 + k];
        c1 += a * lcW[(f0+1)*62 + c*31 + k];
      }
    cfs[h][jl][f0] = c0; cfs[h][jl][f0+1] = c1;
  }
  __syncthreads();
  if (act){
    int dg = t2 & 15, jl = t2 >> 4;
    int j = j0 + jl;
    float s = 0.f;
    if (j < 300){
      const float* pmrow = pm + ((size_t)(b*300 + j))*128 + dg*8;
#pragma unroll
      for (int dd = 0; dd < 8; ++dd){
        int d = dg*8 + dd;
        float acc = sPq[d] + pmrow[dd];
#pragma unroll
        for (int f = 0; f < 32; ++f) acc += cfs[h][jl][f] * ldW[d*32 + f];
        s += vw[d] * tanhf(acc);
      }
    }
    ep[h][jl][dg] = s;
  }
  __syncthreads();
  if (act && t2 < 16){
    int j = j0 + t2;
    if (j < 300){
      float s = 0.f;
#pragma unroll
      for (int dg = 0; dg < 16; ++dg) s += ep[h][t2][dg];
      gstore(&e_ws[b*300 + j], s);
    }
  }
  __syncthreads();
}

// ---------------- B: pq (4-seg) + energy (2 halves x 2 rounds) ----------------
__device__ __forceinline__ void pq_energy(int b, int jt, const float* __restrict__ ah,
    const float* __restrict__ qWT, const float* __restrict__ aw, const float* __restrict__ awc,
    const float* __restrict__ lcW, const float* __restrict__ ldW, const float* __restrict__ vw,
    const float* __restrict__ pm, float* __restrict__ e_ws, int tid){
  __shared__ float sAh[1024];
  __shared__ float pqs[512];
  __shared__ float sPq[128];
  for (int i = tid; i < 1024; i += 512) sAh[i] = ah[b*1024 + i];   // cached (ring slot)
  __syncthreads();
  int d = tid & 127, seg = tid >> 7;   // 4 u-segments of 256
  const float* qt = qWT + (size_t)(seg*256)*128 + d;
  const float* sh = sAh + seg*256;
  float a0 = 0.f, a1 = 0.f, a2 = 0.f, a3 = 0.f;
  for (int u = 0; u < 256; u += 4){
    a0 += sh[u]   * qt[(size_t)u*128];
    a1 += sh[u+1] * qt[(size_t)(u+1)*128];
    a2 += sh[u+2] * qt[(size_t)(u+2)*128];
    a3 += sh[u+3] * qt[(size_t)(u+3)*128];
  }
  pqs[seg*128 + d] = (a0 + a1) + (a2 + a3);
  __syncthreads();
  if (tid < 128) sPq[tid] = (pqs[tid] + pqs[128+tid]) + (pqs[256+tid] + pqs[384+tid]);
  __syncthreads();
  int h = tid >> 8, t2 = tid & 255;
  for (int r = 0; r < 2; ++r){
    int tile = r*16 + jt*2 + h;
    energy_tile(b, tile, tile < 19, h, aw, awc, lcW, ldW, vw, sPq, pm, e_ws, t2);
  }
}

// ---------------- distributed dec output slice: block (b,jt) does 10 mel cols ----------------
__device__ __forceinline__ void dec_out_slice(int b, int jt,
    const float* __restrict__ dh, const float* __restrict__ ctx,
    const float* __restrict__ pWT, const float* __restrict__ projb,
    const float* __restrict__ gateW, const float* __restrict__ gateb,
    float* __restrict__ out, int s, int tid){
  __shared__ float sX[1536];
  __shared__ float melp[48][11];
  __shared__ float gatep[32];
  for (int i = tid; i < 1024; i += 512) sX[i] = dh[b*1024 + i];     // cached (ring slot)
  if (tid < 512) { int i = tid; sX[1024 + i] = ctx[b*512 + i]; }    // cached (ring slot)
  __syncthreads();
  if (tid < 480){
    int mi = tid % 10, kseg = tid / 10;     // 48 k-segments of 32
    int m = jt*10 + mi;
    const float* pw = pWT + m;
    int k0 = kseg*32;
    float a0 = 0.f, a1 = 0.f;
#pragma unroll 8
    for (int k = 0; k < 32; k += 2){
      a0 += sX[k0+k]   * pw[(size_t)(k0+k)*80];
      a1 += sX[k0+k+1] * pw[(size_t)(k0+k+1)*80];
    }
    melp[kseg][mi] = a0 + a1;
  } else if (jt == 0){
    int kseg = tid - 480;                    // 32 segs of 48
    int k0 = kseg*48;
    float a = 0.f;
    for (int k = 0; k < 48; ++k) a += sX[k0+k] * gateW[k0+k];
    gatep[kseg] = a;
  }
  __syncthreads();
  if (tid < 10){
    float s2 = projb[jt*10 + tid];
    for (int q = 0; q < 48; ++q) s2 += melp[q][tid];
    out[(size_t)b*40000 + (size_t)(jt*10 + tid)*500 + s] = s2;
  }
  if (jt == 0 && tid == 10){
    float s2 = gateb[0];
    for (int q = 0; q < 32; ++q) s2 += gatep[q];
    out[1280000 + (size_t)b*500 + s] = s2;
  }
  __syncthreads();
}

// ---------------- C: softmax + ctx (8-way d-split, 512 thr) ----------------
__device__ __forceinline__ void soft_phase(int b, int dsl, const float* __restrict__ e_ws,
    const int* __restrict__ lens, const float* __restrict__ mem,
    float* __restrict__ aw, float* __restrict__ awc, float* __restrict__ ctx,
    float* __restrict__ out, int t, int tid){
  __shared__ float se[300];
  __shared__ float sa[300];
  __shared__ float red[512];
  int len = lens[b];
  for (int j = tid; j < 300; j += 512) se[j] = gload(&e_ws[b*300 + j]);
  __syncthreads();
  float m = -1e30f;
  for (int j = tid; j < len; j += 512) m = fmaxf(m, se[j]);
  red[tid] = m; __syncthreads();
  for (int s = 256; s > 0; s >>= 1){ if (tid < s) red[tid] = fmaxf(red[tid], red[tid + s]); __syncthreads(); }
  float mx = red[0]; __syncthreads();
  float ssum = 0.f;
  for (int j = tid; j < len; j += 512) ssum += expf(se[j] - mx);
  red[tid] = ssum; __syncthreads();
  for (int s = 256; s > 0; s >>= 1){ if (tid < s) red[tid] += red[tid + s]; __syncthreads(); }
  float inv = 1.f/red[0];
  __syncthreads();
  float* al = out + 1296000 + (size_t)b*150000 + (size_t)t*300;
  for (int j = tid; j < 300; j += 512){
    float v = (j < len) ? expf(se[j] - mx)*inv : 0.f;
    sa[j] = v;
    if (dsl == 0){
      gstore(&aw[b*300 + j], v);
      gstore(&awc[b*300 + j], gload(&awc[b*300 + j]) + v);
      al[j] = v;
    }
  }
  __syncthreads();
  int d = dsl*64 + (tid & 63), jq = tid >> 6;   // 8-way j-split
  int chunk = (len + 7) >> 3;
  int j0 = jq*chunk, j1 = min(len, j0 + chunk);
  float a0 = 0.f, a1 = 0.f;
  const float* mb = mem + (size_t)b*153600 + d;
  int j = j0;
  for (; j + 1 < j1; j += 2){
    a0 += sa[j]   * mb[(size_t)j*512];
    a1 += sa[j+1] * mb[(size_t)(j+1)*512];
  }
  if (j < j1) a0 += sa[j]*mb[(size_t)j*512];
  red[tid] = a0 + a1; __syncthreads();
  if (jq == 0){
    int ln = tid & 63;
    float s = 0.f;
#pragma unroll
    for (int q = 0; q < 8; ++q) s += red[ln + 64*q];
    gstore(&ctx[b*512 + d], s);
  }
  __syncthreads();
}

// ---------------- persistent loop ----------------
struct DecParams {
  const float *memory;
  const int   *lens;
  const float *attWih, *attWhh, *attBih, *attBhh;
  const float *decBih, *decBhh;
  const float *lcW, *ldW, *vw, *projb, *gateW, *gateb;
  float *ws, *out;
};

__global__ void __launch_bounds__(512, 2) k_loop(DecParams p){
  int wg = blockIdx.x, tid = threadIdx.x;
  float* ws = p.ws;
  const unsigned short* decins = (const unsigned short*)(ws + OFF_DECINS);
  const unsigned short* wlo = (const unsigned short*)(ws + OFF_WLO);
  const unsigned short* whi = (const unsigned short*)(ws + OFF_WHI);
  float* e_ws = ws + OFF_E;
  float* pm = ws + OFF_PM;
  float* AC = ws + OFF_AC;
  float* DC = ws + OFF_DC;
  float* aw = ws + OFF_AW;
  float* awc = ws + OFF_AWC;
  float* qWT = ws + OFF_QWT;
  float* pWT = ws + OFF_PROJWT;
  unsigned* slots = (unsigned*)(ws + OFF_SLOTS);
  unsigned ep = 0;
  int b = wg >> 3, jt = wg & 7;

#define AHR(s) (ws + OFF_AHR + (size_t)(s)*32768)
#define DHR(s) (ws + OFF_DHR + (size_t)(s)*32768)
#define CXR(s) (ws + OFF_CXR + (size_t)(s)*16384)

  // prologue: zero all ring slots at the coherence point (write-through)
  for (unsigned i = (unsigned)wg*512u + tid; i < (unsigned)RINGS_N; i += 131072u)
    gstore(ws + OFF_AHR + i, 0.f);
  gbar(slots, ++ep);

  // A(0): ah(0) = LSTM([x_0, ctx=0], h=0) -> AHR(1)
  lstm_block<true,false>(wg, p.attWih, p.attWhh, nullptr, nullptr, p.attBih, p.attBhh,
                         decins, PRE, CXR(0), AHR(0), 1792, AC, AHR(1), tid);
  gbar(slots, ++ep);

  for (int t = 0; t < TDEC; ++t){
    int cu = (t + 1) % RD, pr = t % RD, nx = (t + 2) % RD;
    // B~: pq + energy; distributed dec-out of step t-1
    pq_energy(b, jt, AHR(cu), qWT, aw, awc, p.lcW, p.ldW, p.vw, pm, e_ws, tid);
    if (t > 0)
      dec_out_slice(b, jt, DHR(pr), CXR(pr), pWT, p.projb, p.gateW, p.gateb, p.out, t - 1, tid);
    gbar(slots, ++ep);
    // C: softmax + ctx
    soft_phase(b, jt, e_ws, p.lens, p.memory, aw, awc, CXR(cu), p.out, t, tid);
    gbar(slots, ++ep);
    // D~: dec LSTM (bf16 W) + att LSTM (t+1)
    lstm_block<false,true>(wg, nullptr, nullptr, wlo, whi, p.decBih, p.decBhh,
                           AHR(cu), 1024, CXR(cu), DHR(pr), 2560, DC, DHR(cu), tid);
    if (t + 1 < TDEC)
      lstm_block<true,false>(wg, p.attWih, p.attWhh, nullptr, nullptr, p.attBih, p.attBhh,
                             decins + (size_t)(t + 1)*NB*PRE, PRE, CXR(cu), AHR(cu), 1792,
                             AC, AHR(nx), tid);
    gbar(slots, ++ep);
  }
  // epilogue: dec-out of final step (t=499): dh/ctx in slot (500%4)=0
  dec_out_slice(b, jt, DHR(500 % RD), CXR(500 % RD), pWT, p.projb, p.gateW, p.gateb,
                p.out, TDEC - 1, tid);
#undef AHR
#undef DHR
#undef CXR
}

// ---------------- host ----------------
extern "C" void kernel_launch(void* const* d_in, const int* in_sizes, int n_in,
                              void* d_out, int out_size, void* d_ws, size_t ws_size,
                              hipStream_t stream) {
  const float* memory   = (const float*)d_in[0];
  const float* dec_in   = (const float*)d_in[1];
  const int*   lens     = (const int*)  d_in[2];
  const float* pre_W1   = (const float*)d_in[3];
  const float* pre_W2   = (const float*)d_in[4];
  const float* att_Wih  = (const float*)d_in[5];
  const float* att_Whh  = (const float*)d_in[6];
  const float* att_bih  = (const float*)d_in[7];
  const float* att_bhh  = (const float*)d_in[8];
  const float* q_W      = (const float*)d_in[9];
  const float* m_W      = (const float*)d_in[10];
  const float* v_w      = (const float*)d_in[11];
  const float* lc_W     = (const float*)d_in[12];
  const float* ld_W     = (const float*)d_in[13];
  const float* dec_Wih  = (const float*)d_in[14];
  const float* dec_Whh  = (const float*)d_in[15];
  const float* dec_bih  = (const float*)d_in[16];
  const float* dec_bhh  = (const float*)d_in[17];
  const float* proj_W   = (const float*)d_in[18];
  const float* proj_b   = (const float*)d_in[19];
  const float* gate_W   = (const float*)d_in[20];
  const float* gate_b   = (const float*)d_in[21];
  float* out = (float*)d_out;
  float* ws  = (float*)d_ws;

  // Partitionable (foldlike) split of jax.random.key(1)
  unsigned k10, k11, k20, k21;
  tf2x32(0u, 1u, 0u, 0u, k10, k11);
  tf2x32(0u, 1u, 0u, 1u, k20, k21);

  k_setup<<<1024, 256, 0, stream>>>(ws, q_W, proj_W, m_W, pre_W1, pre_W2, dec_Wih, dec_Whh);
  k_prenet<<<TDEC*NB, 256, 0, stream>>>(dec_in, ws + OFF_W1T, ws + OFF_W2T,
                                        (unsigned short*)(ws + OFF_DECINS), k10, k11, k20, k21);
  k_procmem<<<NB*TENC, 128, 0, stream>>>(memory, ws + OFF_MWT, ws + OFF_PM);

  DecParams hp;
  hp.memory = memory; hp.lens = lens;
  hp.attWih = att_Wih; hp.attWhh = att_Whh; hp.attBih = att_bih; hp.attBhh = att_bhh;
  hp.decBih = dec_bih; hp.decBhh = dec_bhh;
  hp.lcW = lc_W; hp.ldW = ld_W; hp.vw = v_w; hp.projb = proj_b; hp.gateW = gate_W; hp.gateb = gate_b;
  hp.ws = ws; hp.out = out;
  k_loop<<<256, 512, 0, stream>>>(hp);
}